// Round 9
// baseline (360.646 us; speedup 1.0000x reference)
//
#include <hip/hip_runtime.h>
#include <stdint.h>

typedef __attribute__((ext_vector_type(8))) short short8;
typedef __attribute__((ext_vector_type(4))) float f32x4;
typedef __attribute__((ext_vector_type(4))) unsigned int u32x4;

#define CB 256
#define HWN 4096
#define NB 64
#define NCHUNK 16
#define THR 0.5f
#define MAXC 32

// RNE fp32 -> bf16-grid fp32 (final output cast)
static __device__ __forceinline__ float rbf(float x){
  unsigned int u = __builtin_bit_cast(unsigned int, x);
  u = (u + 0x7fffu + ((u >> 16) & 1u)) & 0xffff0000u;
  return __builtin_bit_cast(float, u);
}
// RNE fp32 pair -> packed bf16x2
static __device__ __forceinline__ unsigned int pk2(float a, float b){
  unsigned int ua = __builtin_bit_cast(unsigned int, a);
  unsigned int ub = __builtin_bit_cast(unsigned int, b);
  ua = (ua + 0x7fffu + ((ua >> 16) & 1u)) >> 16;
  ub = (ub + 0x7fffu + ((ub >> 16) & 1u)) & 0xffff0000u;
  return ua | ub;
}
static __device__ __forceinline__ void gld_lds16(const void* g, void* l){
  __builtin_amdgcn_global_load_lds(
      (const __attribute__((address_space(1))) unsigned int*)g,
      (__attribute__((address_space(3))) unsigned int*)l, 16, 0, 0);
}

// ---------------- prep: s2[n] = np-pairwise f32 sum of w[n][c]^2 (raw f32; r7-proven)
//                  AND w_swz: bf16-converted, granule-swizzled staging image of w.
__global__ void vq_prep(const float* __restrict__ wcb, float* __restrict__ s2g,
                        unsigned int* __restrict__ w_swz){
  int n = blockIdx.x * 256 + threadIdx.x;
  const float* row = wcb + (size_t)n * CB;
  // np-pairwise sum of squares (mul-then-add, no fma)
  float blk[2];
  #pragma unroll
  for (int b2 = 0; b2 < 2; ++b2){
    float r[8];
    #pragma unroll
    for (int k = 0; k < 8; ++k){ float x = row[b2*128 + k]; r[k] = __fmul_rn(x, x); }
    for (int t = 1; t < 16; ++t)
      #pragma unroll
      for (int k = 0; k < 8; ++k){
        float x = row[b2*128 + t*8 + k];
        r[k] = __fadd_rn(r[k], __fmul_rn(x, x));
      }
    blk[b2] = __fadd_rn(__fadd_rn(__fadd_rn(r[0],r[1]), __fadd_rn(r[2],r[3])),
                        __fadd_rn(__fadd_rn(r[4],r[5]), __fadd_rn(r[6],r[7])));
  }
  s2g[n] = __fadd_rn(blk[0], blk[1]);
  // staging image: chunk ch = n>>6, row r = n&63; granule qp holds source granule qp^(r&7)
  {
    const int ch = n >> 6, rr = n & 63;
    unsigned int* dst = w_swz + (size_t)ch*8192 + rr*128;   // u32 units (512B/row)
    #pragma unroll
    for (int qp = 0; qp < 32; ++qp){
      int sg = qp ^ (rr & 7);
      f32x4 va = *(const f32x4*)(row + sg*8);
      f32x4 vb = *(const f32x4*)(row + sg*8 + 4);
      u32x4 pk = { pk2(va[0],va[1]), pk2(va[2],va[3]), pk2(vb[0],vb[1]), pk2(vb[2],vb[3]) };
      *(u32x4*)(dst + qp*4) = pk;
    }
  }
}

// ---------------- s1: s1[pos] = np-pairwise f32 sum of z[pos][c]^2 (coalesced)
__global__ void vq_s1(const float* __restrict__ ze, float* __restrict__ s1g){
  int pos = blockIdx.x * 256 + threadIdx.x;
  int b = pos >> 12, hw = pos & 4095;
  const float* zp = ze + (size_t)b * CB * HWN + hw;
  float blk[2];
  #pragma unroll
  for (int b2 = 0; b2 < 2; ++b2){
    float r[8];
    for (int t = 0; t < 16; ++t)
      #pragma unroll
      for (int k = 0; k < 8; ++k){
        float x = zp[(size_t)(b2*128 + t*8 + k) * HWN];
        float q = __fmul_rn(x, x);
        if (t == 0) r[k] = q; else r[k] = __fadd_rn(r[k], q);
      }
    blk[b2] = __fadd_rn(__fadd_rn(__fadd_rn(r[0],r[1]), __fadd_rn(r[2],r[3])),
                        __fadd_rn(__fadd_rn(r[4],r[5]), __fadd_rn(r[6],r[7])));
  }
  s1g[pos] = __fadd_rn(blk[0], blk[1]);
}

// ---------------- main: single-pass MFMA screen + f64 exact re-rank + outputs
__global__ __launch_bounds__(256, 2)
void vq_main(const float* __restrict__ ze, const float* __restrict__ wcb,
             const unsigned int* __restrict__ w_swz,
             const float* __restrict__ s2g, const float* __restrict__ s1g,
             float* __restrict__ out, float* __restrict__ partial)
{
  // [0,32K): zeT bf16 swizzled; [32K,64K): B chunk (in-loop) / overlays (post-loop)
  __shared__ __align__(16) char smem[65536];
  __shared__ float minl[64];
  __shared__ int   cnt[64];
  __shared__ int   list[64][MAXC];

  unsigned int* kd  = (unsigned int*)(smem + 32768);   // overlay: dist-bits min
  int*          ki  = (int*)(smem + 33024);            // overlay: index min
  int*          sel = (int*)(smem + 33280);            // overlay: winner
  float*        red = (float*)(smem + 33536);          // overlay: loss partials

  const int tid = threadIdx.x;
  const int bid = blockIdx.x;
  const int b   = bid >> 6;
  const int hw0 = (bid & 63) * 64;
  const int wid  = tid >> 6;
  const int lane = tid & 63;
  const int l15  = lane & 15;
  const int lq   = lane >> 4;
  const int wr = wid >> 1, wc = wid & 1;

  // ---- phase A: raw f32 z -> bf16 zeT[p][c] (RNE, granule-swizzled)
  {
    const int p  = tid & 63;
    const int cg = tid >> 6;
    const float* zp = ze + (size_t)b * CB * HWN + hw0 + p;
    #pragma unroll
    for (int o = 0; o < 8; ++o){
      int c0 = cg*64 + o*8;
      float v[8];
      #pragma unroll
      for (int i = 0; i < 8; ++i) v[i] = zp[(size_t)(c0 + i) * HWN];
      int g = (c0 >> 3) ^ (p & 7);
      u32x4 pk = { pk2(v[0],v[1]), pk2(v[2],v[3]), pk2(v[4],v[5]), pk2(v[6],v[7]) };
      *(u32x4*)(smem + p*512 + g*16) = pk;
    }
  }
  if (tid < 64){ minl[tid] = 3.4e38f; cnt[tid] = 0; }
  __syncthreads();

  // per-lane row constants: np-exact s1 for the 8 owned output rows
  float szr[8];
  {
    int rowbase = wr*32 + lq*4;
    const float* s1b = s1g + (size_t)b * HWN + hw0;
    #pragma unroll
    for (int m = 0; m < 2; ++m)
      #pragma unroll
      for (int r = 0; r < 4; ++r)
        szr[m*4+r] = s1b[rowbase + m*16 + r];
  }

  const int rA0 = wr*32 + l15, rA1 = rA0 + 16;
  const int rB0 = wc*32 + l15, rB1 = rB0 + 16;

  // =================== single pass: min-track + tightening-threshold collect ==
  for (int ch = 0; ch < NCHUNK; ++ch){
    const int n0 = ch * NB;
    // stage pre-converted, pre-swizzled chunk: pure 16B global->LDS copies
    {
      const char* src = (const char*)(w_swz + (size_t)ch*8192);
      #pragma unroll
      for (int j = 0; j < 8; ++j){
        gld_lds16(src + (j*256 + tid)*16,
                  smem + 32768 + (j*256 + wid*64)*16);   // wave-uniform base
      }
    }
    float sw0 = s2g[n0 + wc*32 + l15];
    float sw1 = s2g[n0 + wc*32 + 16 + l15];
    asm volatile("s_waitcnt vmcnt(0)" ::: "memory");
    __syncthreads();

    f32x4 acc00 = {0,0,0,0}, acc01 = {0,0,0,0}, acc10 = {0,0,0,0}, acc11 = {0,0,0,0};
    #pragma unroll
    for (int ks = 0; ks < 8; ++ks){
      int gk = ks*4 + lq;
      short8 a0 = *(const short8*)(smem +          rA0*512 + ((gk ^ (rA0 & 7)) << 4));
      short8 a1 = *(const short8*)(smem +          rA1*512 + ((gk ^ (rA1 & 7)) << 4));
      short8 b0 = *(const short8*)(smem + 32768 +  rB0*512 + ((gk ^ (rB0 & 7)) << 4));
      short8 b1 = *(const short8*)(smem + 32768 +  rB1*512 + ((gk ^ (rB1 & 7)) << 4));
      acc00 = __builtin_amdgcn_mfma_f32_16x16x32_bf16(a0, b0, acc00, 0, 0, 0);
      acc01 = __builtin_amdgcn_mfma_f32_16x16x32_bf16(a0, b1, acc01, 0, 0, 0);
      acc10 = __builtin_amdgcn_mfma_f32_16x16x32_bf16(a1, b0, acc10, 0, 0, 0);
      acc11 = __builtin_amdgcn_mfma_f32_16x16x32_bf16(a1, b1, acc11, 0, 0, 0);
    }

    // dists (f32, np-form), per-row wave-min, tightening-threshold collection
    float d0v[8], d1v[8], rwm[8];
    #pragma unroll
    for (int m = 0; m < 2; ++m)
      #pragma unroll
      for (int r = 0; r < 4; ++r){
        int i = m*4 + r;
        float sz = szr[i];
        float e0 = (m == 0) ? acc00[r] : acc10[r];
        float e1 = (m == 0) ? acc01[r] : acc11[r];
        d0v[i] = __fsub_rn(__fadd_rn(sz, sw0), 2.0f*e0);
        d1v[i] = __fsub_rn(__fadd_rn(sz, sw1), 2.0f*e1);
        rwm[i] = fminf(d0v[i], d1v[i]);
      }
    #pragma unroll
    for (int i = 0; i < 8; ++i){
      #pragma unroll
      for (int off = 1; off < 16; off <<= 1)
        rwm[i] = fminf(rwm[i], __shfl_xor(rwm[i], off, 64));
    }
    #pragma unroll
    for (int m = 0; m < 2; ++m)
      #pragma unroll
      for (int r = 0; r < 4; ++r){
        int i = m*4 + r;
        int row = wr*32 + m*16 + lq*4 + r;
        if (l15 == 0)
          atomicMin((int*)&minl[row], __float_as_int(rwm[i]));  // positive floats: int-order safe
        float thr = fminf(minl[row], rwm[i]) + THR;   // >= final_min + THR  -> never under-collects
        if (d0v[i] <= thr){
          int s = atomicAdd(&cnt[row], 1);
          if (s < MAXC) list[row][s] = n0 + wc*32 + l15;
        }
        if (d1v[i] <= thr){
          int s = atomicAdd(&cnt[row], 1);
          if (s < MAXC) list[row][s] = n0 + wc*32 + 16 + l15;
        }
      }
    __syncthreads();   // all reads of B-chunk done before next staging
  }

  // =================== exact f64 re-rank (r7-proven math), 2-phase atomic pick
  if (tid < 64){ kd[tid] = 0xffffffffu; ki[tid] = 0x7fffffff; }
  __syncthreads();

  {
    const int pos = tid & 63;
    const int sq  = tid >> 6;
    const int c_  = min(cnt[pos], MAXC);
    const float* zr = ze + (size_t)b * CB * HWN + hw0 + pos;
    const float s1p = s1g[(size_t)b * HWN + hw0 + pos];
    float dloc[8]; int nloc = 0;
    for (int slot = sq; slot < c_; slot += 4){
      int code = list[pos][slot];
      const float* wrow = wcb + (size_t)code * CB;
      double a = 0.0;
      #pragma unroll 8
      for (int c = 0; c < 256; ++c)
        a = fma((double)zr[(size_t)c * HWN], (double)wrow[c], a);
      float e32 = (float)a;
      float d = __fsub_rn(__fadd_rn(s1p, s2g[code]), __fmul_rn(2.0f, e32));
      dloc[nloc++] = d;
      atomicMin(&kd[pos], __float_as_uint(d));
    }
    __syncthreads();
    nloc = 0;
    for (int slot = sq; slot < c_; slot += 4){
      int code = list[pos][slot];
      if (__float_as_uint(dloc[nloc++]) == kd[pos])
        atomicMin(&ki[pos], code);     // exact tie -> lowest index (np first-occurrence)
    }
  }
  __syncthreads();

  if (tid < 64){
    if (cnt[tid] <= MAXC){
      sel[tid] = ki[tid];
    } else {
      // overflow fallback: full exact scan (correct; statistically never taken)
      const float* zr = ze + (size_t)b * CB * HWN + hw0 + tid;
      const float s1p = s1g[(size_t)b * HWN + hw0 + tid];
      float bv = 3.4e38f; int bi = 0;
      for (int n = 0; n < 1024; ++n){
        double a = 0.0;
        for (int c = 0; c < 256; ++c)
          a = fma((double)zr[(size_t)c * HWN], (double)wcb[(size_t)n * CB + c], a);
        float e32 = (float)a;
        float d = __fsub_rn(__fadd_rn(s1p, s2g[n]), __fmul_rn(2.0f, e32));
        if (d < bv){ bv = d; bi = n; }
      }
      sel[tid] = bi;
    }
  }
  __syncthreads();

  // =================== epilogue: STE output (f32 -> bf16 cast) + loss ========
  {
    const int p    = tid & 63;
    const int cseg = tid >> 6;
    const int code = sel[p];
    const float* qrow = wcb + (size_t)code * CB;
    const float* zcol = ze  + (size_t)b * CB * HWN + hw0 + p;
    float*       outb = out + (size_t)b * CB * HWN + hw0 + p;
    float lacc = 0.f;
    for (int k = 0; k < 64; ++k){
      int c = cseg*64 + k;
      float zq = qrow[c];
      float zf = zcol[(size_t)c * HWN];
      float st = __fadd_rn(zf, __fsub_rn(zq, zf));   // f32 STE
      outb[(size_t)c * HWN] = rbf(st);               // final bf16 cast
      float dd = __fsub_rn(zf, zq);
      lacc = __fadd_rn(lacc, __fmul_rn(dd, dd));
    }
    red[tid] = lacc;
  }
  __syncthreads();
  for (int s = 128; s > 0; s >>= 1){
    if (tid < s) red[tid] += red[tid + s];
    __syncthreads();
  }
  if (tid == 0) partial[bid] = red[0];
}

// ---------------- loss: vq[b] = fl(m + fl(0.25*m)), m = fl(sum/2^20); bf16 cast
__global__ void vq_loss(const float* __restrict__ partial, float* __restrict__ outl){
  int t = threadIdx.x;
  if (t < 16){
    float s = 0.f;
    for (int j = 0; j < 64; ++j) s += partial[t*64 + j];
    float m = __fmul_rn(s, 1.0f / 1048576.0f);
    outl[t] = rbf(__fadd_rn(m, __fmul_rn(0.25f, m)));
  }
}

extern "C" void kernel_launch(void* const* d_in, const int* in_sizes, int n_in,
                              void* d_out, int out_size, void* d_ws, size_t ws_size,
                              hipStream_t stream)
{
  const float* ze  = (const float*)d_in[0];   // z_e  [16,256,64,64] raw f32
  const float* wcb = (const float*)d_in[1];   // embed_w [1024,256] raw f32
  float* out = (float*)d_out;                 // z_q_st (bf16-grid f32) + vq_loss[16]
  float* s2g     = (float*)d_ws;              // [1024]
  float* s1gbuf  = s2g + 1024;                // [65536]
  float* partial = s1gbuf + 65536;            // [1024]
  unsigned int* w_swz = (unsigned int*)(partial + 1024);  // [1024*128] u32 = 512 KB

  hipLaunchKernelGGL(vq_prep, dim3(4),    dim3(256), 0, stream, wcb, s2g, w_swz);
  hipLaunchKernelGGL(vq_s1,   dim3(256),  dim3(256), 0, stream, ze, s1gbuf);
  hipLaunchKernelGGL(vq_main, dim3(1024), dim3(256), 0, stream,
                     ze, wcb, w_swz, s2g, s1gbuf, out, partial);
  hipLaunchKernelGGL(vq_loss, dim3(1),    dim3(64), 0, stream,
                     partial, out + (size_t)16 * 256 * 4096);
}